// Round 12
// baseline (284.437 us; speedup 1.0000x reference)
//
#include <hip/hip_runtime.h>
#include <hip/hip_bf16.h>

// Problem constants
#define B_ 8
#define S_ 4096
#define H_ 512

using short8 = __attribute__((ext_vector_type(8))) short;
using f32x4  = __attribute__((ext_vector_type(4))) float;

// ---------- helpers ----------
__device__ __forceinline__ float bf2f(unsigned u16) {
    return __uint_as_float(u16 << 16);
}
__device__ __forceinline__ unsigned pk2bf(float x, float y) {
    __hip_bfloat162 h = __float22bfloat162_rn(make_float2(x, y));  // v_cvt_pk_bf16_f32
    return *reinterpret_cast<unsigned*>(&h);
}
__device__ __forceinline__ float softplus_f(float x) {
    float sp = __logf(1.0f + __expf(x));
    return x > 15.0f ? x : sp;
}

// raw barrier (no counter drain) with compiler memory fences
#define BAR() do { asm volatile("" ::: "memory"); \
                   __builtin_amdgcn_s_barrier(); \
                   asm volatile("" ::: "memory"); } while (0)

// ---------- Pass 1 (FUSED, was convert_bf16 + gemm): fp32-in bf16-MFMA GEMM --
// Plateau post-mortem (r4-r11): six sync structures all land at 58-62 us with
// identical counters -> schedule knobs are exhausted. The remaining structural
// waste was the separate convert pass (~100 MB HBM, ~20 us + launch gap) that
// existed only to feed global_load_lds. r1 MEASURED that in-loop fp32->bf16
// staging costs ~nothing (66 us in a worse structure). So: read A/W fp32
// directly, cvt_pk during staging, delete pass 1.
// Skeleton = r6 (proven best): 128x128, BK=32, 2-slot ring, 4 waves,
// 16 MFMA/slice, B q/r row remap, packed {q,r} epilogue, XCD swizzle.
// Staging = T14 reg-staged: loads for slice g+1 issued one phase early (plain
// C++ -> compiler inserts the counted vmcnt exactly before the cvt uses them);
// ds_write into the slot freed by this phase's entry barrier; explicit
// lgkmcnt(0) before the raw end barrier (cross-wave visibility). No manual
// vmcnt anywhere -> loads for g+2 stay in flight across barriers.
// LDS: reg-staging frees the layout -> pad rows to LDT=40 elems (80 B,
// 16B-aligned rows; stride 20 dwords -> ~2-way banks = free). 40 KB total.
#define TM 128
#define TN 128
#define BK 32
#define LDT 40

__global__ __launch_bounds__(256, 4)
void gemm_softplus(const float* __restrict__ Af,
                   const float* __restrict__ Wf,
                   const float* __restrict__ bias,
                   unsigned* __restrict__ QR) {
    __shared__ unsigned short As[2][TM * LDT];   // 10 KB per slot
    __shared__ unsigned short Bs[2][TN * LDT];   // total 40 KB -> 4 blocks/CU

    // XCD-chunked swizzle: 2048 blocks = 8 XCD * 256; the 8 blocks sharing an
    // A strip land on ONE XCD (measured: FETCH 265 -> 22 MB in r1/r4).
    const int bid     = blockIdx.x;
    const int logical = (bid & 7) * 256 + (bid >> 3);
    const int bm = logical >> 3;     // 0..255
    const int bn = logical & 7;      // 0..7

    const int t    = threadIdx.x;
    const int wave = t >> 6;
    const int lane = t & 63;
    const int wm  = (wave >> 1) * 64;
    const int wn  = (wave & 1) * 64;
    const int l15 = lane & 15;
    const int l4  = lane >> 4;

    const int m0 = bm * TM;

    // ---- staging geometry: thread t covers row t>>1, k-half (t&1)*16 ----
    const int srow = t >> 1;             // 0..127
    const int sh   = (t & 1) * 16;       // fp32/bf16 elem offset within row
    // B tile row -> W row (r6-verified): rows 0..31 -> q cols bn*64+0..31,
    // 32..63 -> same +512 (r), 64..95 -> q +32, 96..127 -> r +32.
    const int nsr = bn * 64 + (srow & 31) + ((srow & 64) >> 1) + ((srow & 32) << 4);
    const float* aS = Af + (size_t)(m0 + srow) * 512 + sh;
    const float* bS = Wf + (size_t)nsr * 512 + sh;
    unsigned short* aD0 = &As[0][srow * LDT + sh];
    unsigned short* aD1 = &As[1][srow * LDT + sh];
    unsigned short* bD0 = &Bs[0][srow * LDT + sh];
    unsigned short* bD1 = &Bs[1][srow * LDT + sh];

    // ---- ds_read geometry (padded, no swizzle) ----
    const int aoff = (wm + l15) * LDT + l4 * 8;   // + i*16*LDT per fragment
    const int boff = (wn + l15) * LDT + l4 * 8;

    f32x4 acc[4][4] = {};
    float4 ra[4], rb[4];                 // staging regs (single buffer, 32 VGPR)

#define LOADREGS(s) do { \
    const float4* _ap = (const float4*)(aS + (s) * BK); \
    const float4* _bp = (const float4*)(bS + (s) * BK); \
    _Pragma("unroll") for (int jj = 0; jj < 4; ++jj) { \
        ra[jj] = _ap[jj]; rb[jj] = _bp[jj]; } \
} while (0)

#define CVTWRITE(s) do { \
    unsigned short* _ad = ((s) & 1) ? aD1 : aD0; \
    unsigned short* _bd = ((s) & 1) ? bD1 : bD0; \
    uint4 w; \
    w.x = pk2bf(ra[0].x, ra[0].y); w.y = pk2bf(ra[0].z, ra[0].w); \
    w.z = pk2bf(ra[1].x, ra[1].y); w.w = pk2bf(ra[1].z, ra[1].w); \
    *(uint4*)_ad = w; \
    w.x = pk2bf(ra[2].x, ra[2].y); w.y = pk2bf(ra[2].z, ra[2].w); \
    w.z = pk2bf(ra[3].x, ra[3].y); w.w = pk2bf(ra[3].z, ra[3].w); \
    *(uint4*)(_ad + 8) = w; \
    w.x = pk2bf(rb[0].x, rb[0].y); w.y = pk2bf(rb[0].z, rb[0].w); \
    w.z = pk2bf(rb[1].x, rb[1].y); w.w = pk2bf(rb[1].z, rb[1].w); \
    *(uint4*)_bd = w; \
    w.x = pk2bf(rb[2].x, rb[2].y); w.y = pk2bf(rb[2].z, rb[2].w); \
    w.z = pk2bf(rb[3].x, rb[3].y); w.w = pk2bf(rb[3].z, rb[3].w); \
    *(uint4*)(_bd + 8) = w; \
} while (0)

// Phase g: entry barrier already passed (slot (g+1)&1's readers done).
// ds_read frags of g -> cvt+write slice g+1 (compiler inserts the vmcnt for
// its regs; they were loaded one full phase ago) -> issue loads for g+2 ->
// MFMA g -> lgkmcnt(0) (writes visible) -> barrier.
#define PHASE(g, DW, DL) do { \
    const unsigned short* _a = &As[(g) & 1][0]; \
    const unsigned short* _b = &Bs[(g) & 1][0]; \
    short8 af[4], bf[4]; \
    _Pragma("unroll") for (int ii = 0; ii < 4; ++ii) { \
        af[ii] = *(const short8*)(_a + aoff + ii * 16 * LDT); \
        bf[ii] = *(const short8*)(_b + boff + ii * 16 * LDT); \
    } \
    if (DW) CVTWRITE((g) + 1); \
    if (DL) LOADREGS((g) + 2); \
    __builtin_amdgcn_s_setprio(1); \
    _Pragma("unroll") for (int ii = 0; ii < 4; ++ii) \
    _Pragma("unroll") for (int jj = 0; jj < 4; ++jj) \
        acc[ii][jj] = __builtin_amdgcn_mfma_f32_16x16x32_bf16(af[ii], bf[jj], acc[ii][jj], 0, 0, 0); \
    __builtin_amdgcn_s_setprio(0); \
    asm volatile("s_waitcnt lgkmcnt(0)" ::: "memory"); \
    BAR(); \
} while (0)

    // prologue: slice 0 into slot 0; issue slice-1 loads; sync
    LOADREGS(0);
    CVTWRITE(0);
    LOADREGS(1);
    asm volatile("s_waitcnt lgkmcnt(0)" ::: "memory");
    BAR();

    for (int g = 0; g < 14; ++g) PHASE(g, 1, 1);   // writes 1..14, loads 2..15
    PHASE(14, 1, 0);                               // writes slice 15
    PHASE(15, 0, 0);                               // tail

#undef PHASE
#undef CVTWRITE
#undef LOADREGS

    // epilogue (r6-verified): bias + softplus, packed {q,r} 4B stores
#pragma unroll
    for (int j = 0; j < 2; ++j) {
        const int h  = bn * 64 + (wn >> 1) + j * 16 + l15;  // 0..511
        const float bq = bias[h];
        const float br = bias[h + 512];
#pragma unroll
        for (int i = 0; i < 4; ++i) {
            const int mb = m0 + wm + i * 16 + l4 * 4;
#pragma unroll
            for (int r = 0; r < 4; ++r) {
                const float qv = softplus_f(acc[i][j][r] + bq);
                const float rv = softplus_f(acc[i][j + 2][r] + br);
                QR[(size_t)(mb + r) * 512 + h] = pk2bf(qv, rv);
            }
        }
    }
}

// ---------- Pass 2: chunked Kalman scan (r11-verified, unchanged) ----------
// 16 chunks of 256 steps, 64-step warm-up; 1 h-column/thread, 8-buffer
// rotation, depth-4 prefetch; ng in {32,40} -> unguarded COMP.
#define CHUNK 256
#define WARM 64

__global__ __launch_bounds__(256, 2)
void kalman_scan(const float* __restrict__ z,
                 const unsigned* __restrict__ QR,
                 float* __restrict__ out) {
    const int t     = threadIdx.x;
    const int hb    = blockIdx.x & 1;
    const int b     = (blockIdx.x >> 1) & 7;
    const int chunk = blockIdx.x >> 4;          // 0..15
    const int h     = hb * 256 + t;             // 0..511
    const int s0    = chunk << 8;               // chunk*256
    const int sw    = (chunk == 0) ? 0 : (s0 - WARM);
    const size_t base = ((size_t)(b * S_ + sw)) * 512 + h;

    const float*    zp  = z + base;             // stride 512 floats / step
    const unsigned* qrp = (const unsigned*)QR + base;
    float*          op  = out + base;

    const int ng    = ((s0 + CHUNK) - sw) >> 3;   // 32 (chunk 0) or 40
    const int skipg = (s0 - sw) >> 3;             // 0 or 8

    float    Z0[8], Z1[8], Z2[8], Z3[8], Z4[8], Z5[8], Z6[8], Z7[8];
    unsigned Q0[8], Q1[8], Q2[8], Q3[8], Q4[8], Q5[8], Q6[8], Q7[8];

#define LOADG(g, Zb, Qb) { const int _o = (g) * 8;                          \
    _Pragma("unroll") for (int u = 0; u < 8; ++u) {                         \
        Zb[u] = zp[(size_t)(_o + u) * 512]; Qb[u] = qrp[(size_t)(_o + u) * 512]; } }

#define COMP(g, Zb, Qb) { const int _o = (g) * 8; const bool _st = (g) >= skipg; \
    _Pragma("unroll") for (int u = 0; u < 8; ++u) {                         \
        const float q  = bf2f(Qb[u] & 0xffffu);                             \
        const float r  = bf2f(Qb[u] >> 16);                                 \
        const float Pp = P + q, rr = r + 1e-6f;                             \
        const float K  = Pp * __builtin_amdgcn_rcpf(Pp + rr);               \
        state = fmaf(K, Zb[u] - state, state); P = rr * K;                  \
        if (_st) op[(size_t)(_o + u) * 512] = state; } }

    LOADG(0, Z0, Q0); LOADG(1, Z1, Q1); LOADG(2, Z2, Q2); LOADG(3, Z3, Q3);

    float state = Z0[0];   // state init = z[sw]
    float P = 0.1f;

    for (int g = 0; g < ng; g += 8) {
        if (g + 4  < ng) LOADG(g + 4,  Z4, Q4); COMP(g,     Z0, Q0);
        if (g + 5  < ng) LOADG(g + 5,  Z5, Q5); COMP(g + 1, Z1, Q1);
        if (g + 6  < ng) LOADG(g + 6,  Z6, Q6); COMP(g + 2, Z2, Q2);
        if (g + 7  < ng) LOADG(g + 7,  Z7, Q7); COMP(g + 3, Z3, Q3);
        if (g + 8  < ng) LOADG(g + 8,  Z0, Q0); COMP(g + 4, Z4, Q4);
        if (g + 9  < ng) LOADG(g + 9,  Z1, Q1); COMP(g + 5, Z5, Q5);
        if (g + 10 < ng) LOADG(g + 10, Z2, Q2); COMP(g + 6, Z6, Q6);
        if (g + 11 < ng) LOADG(g + 11, Z3, Q3); COMP(g + 7, Z7, Q7);
    }
#undef LOADG
#undef COMP
}

extern "C" void kernel_launch(void* const* d_in, const int* in_sizes, int n_in,
                              void* d_out, int out_size, void* d_ws, size_t ws_size,
                              hipStream_t stream) {
    const float* lstm = (const float*)d_in[0];   // (8,4096,512) fp32
    const float* Wm   = (const float*)d_in[1];   // (1024,512)  fp32
    const float* bias = (const float*)d_in[2];   // (1024,)     fp32

    unsigned* QRw = (unsigned*)d_ws;             // packed {q,r} bf16x2, 64 MB

    // Fused GEMM reads fp32 inputs directly (convert pass deleted).
    // 256 M-tiles x 8 N-tiles = 2048 blocks of 256 threads (4 blocks/CU)
    hipLaunchKernelGGL(gemm_softplus, dim3(2048), dim3(256), 0, stream,
                       lstm, Wm, bias, QRw);

    // 2 h-halves * 8 batches * 16 chunks = 256 blocks of 256 threads
    hipLaunchKernelGGL(kalman_scan, dim3(256), dim3(256), 0, stream,
                       lstm, QRw, (float*)d_out);
}

// Round 13
// 217.752 us; speedup vs baseline: 1.3062x; 1.3062x over previous
//
#include <hip/hip_runtime.h>
#include <hip/hip_bf16.h>

// Problem constants
#define B_ 8
#define S_ 4096
#define H_ 512

using short8 = __attribute__((ext_vector_type(8))) short;
using f32x4  = __attribute__((ext_vector_type(4))) float;

// ---------- helpers ----------
__device__ __forceinline__ float bf2f(unsigned u16) {
    return __uint_as_float(u16 << 16);
}
__device__ __forceinline__ unsigned pk2bf(float x, float y) {
    __hip_bfloat162 h = __float22bfloat162_rn(make_float2(x, y));  // v_cvt_pk_bf16_f32
    return *reinterpret_cast<unsigned*>(&h);
}
__device__ __forceinline__ float softplus_f(float x) {
    float sp = __logf(1.0f + __expf(x));
    return x > 15.0f ? x : sp;
}

// raw barrier (no counter drain) with compiler memory fences
#define BAR() do { asm volatile("" ::: "memory"); \
                   __builtin_amdgcn_s_barrier(); \
                   asm volatile("" ::: "memory"); } while (0)

// ---------- Pass 1 (fused convert+GEMM): fp32-in bf16-MFMA GEMM ----------
// r12 post-mortem: fusion itself WORKED (total - GEMM = 119 us vs 133.5 in
// r11 -> convert-pass removal reclaimed ~15-20 us), but __launch_bounds__
// (256,4) pinned VGPR to 64 while live state is ~130 (acc 64 + ra/rb 32 +
// frags + addrs) -> scratch spill: WRITE 175 MB (+109 spill), MfmaUtil 8.5%.
// Same failure mode as round 5. FIX: bounds (256,2) -> allocator free up to
// 256 VGPR, no spill; occupancy drops to 2 blocks/CU, which r4-vs-r6 measured
// as a null knob (59.4 vs 58.5 us) on this GEMM family.
// Skeleton = r6 (proven best): 128x128, BK=32, 2-slot ring, 4 waves,
// 16 MFMA/slice, B q/r row remap, packed {q,r} epilogue, XCD swizzle.
// Staging = T14 reg-staged: loads for slice g+1 issued one phase early (plain
// C++ -> compiler inserts the counted vmcnt exactly before the cvt uses them);
// ds_write into the slot freed by this phase's entry barrier; explicit
// lgkmcnt(0) before the raw end barrier (cross-wave visibility). No manual
// vmcnt anywhere -> loads for g+2 stay in flight across barriers.
// LDS: padded rows LDT=40 elems (80 B); staging write and fragment read are
// both 2-way bank aliasing per 16-lane quarter = free (m136). 40 KB total.
#define TM 128
#define TN 128
#define BK 32
#define LDT 40

__global__ __launch_bounds__(256, 2)
void gemm_softplus(const float* __restrict__ Af,
                   const float* __restrict__ Wf,
                   const float* __restrict__ bias,
                   unsigned* __restrict__ QR) {
    __shared__ unsigned short As[2][TM * LDT];   // 10 KB per slot
    __shared__ unsigned short Bs[2][TN * LDT];   // total 40 KB

    // XCD-chunked swizzle: 2048 blocks = 8 XCD * 256; the 8 blocks sharing an
    // A strip land on ONE XCD (measured: FETCH 265 -> 22 MB in r1/r4).
    const int bid     = blockIdx.x;
    const int logical = (bid & 7) * 256 + (bid >> 3);
    const int bm = logical >> 3;     // 0..255
    const int bn = logical & 7;      // 0..7

    const int t    = threadIdx.x;
    const int wave = t >> 6;
    const int lane = t & 63;
    const int wm  = (wave >> 1) * 64;
    const int wn  = (wave & 1) * 64;
    const int l15 = lane & 15;
    const int l4  = lane >> 4;

    const int m0 = bm * TM;

    // ---- staging geometry: thread t covers row t>>1, k-half (t&1)*16 ----
    const int srow = t >> 1;             // 0..127
    const int sh   = (t & 1) * 16;       // fp32/bf16 elem offset within row
    // B tile row -> W row (r6-verified): rows 0..31 -> q cols bn*64+0..31,
    // 32..63 -> same +512 (r), 64..95 -> q +32, 96..127 -> r +32.
    const int nsr = bn * 64 + (srow & 31) + ((srow & 64) >> 1) + ((srow & 32) << 4);
    const float* aS = Af + (size_t)(m0 + srow) * 512 + sh;
    const float* bS = Wf + (size_t)nsr * 512 + sh;
    unsigned short* aD0 = &As[0][srow * LDT + sh];
    unsigned short* aD1 = &As[1][srow * LDT + sh];
    unsigned short* bD0 = &Bs[0][srow * LDT + sh];
    unsigned short* bD1 = &Bs[1][srow * LDT + sh];

    // ---- ds_read geometry (padded, no swizzle) ----
    const int aoff = (wm + l15) * LDT + l4 * 8;   // + i*16*LDT per fragment
    const int boff = (wn + l15) * LDT + l4 * 8;

    f32x4 acc[4][4] = {};
    float4 ra[4], rb[4];                 // staging regs (single buffer, 32 VGPR)

#define LOADREGS(s) do { \
    const float4* _ap = (const float4*)(aS + (s) * BK); \
    const float4* _bp = (const float4*)(bS + (s) * BK); \
    _Pragma("unroll") for (int jj = 0; jj < 4; ++jj) { \
        ra[jj] = _ap[jj]; rb[jj] = _bp[jj]; } \
} while (0)

#define CVTWRITE(s) do { \
    unsigned short* _ad = ((s) & 1) ? aD1 : aD0; \
    unsigned short* _bd = ((s) & 1) ? bD1 : bD0; \
    uint4 w; \
    w.x = pk2bf(ra[0].x, ra[0].y); w.y = pk2bf(ra[0].z, ra[0].w); \
    w.z = pk2bf(ra[1].x, ra[1].y); w.w = pk2bf(ra[1].z, ra[1].w); \
    *(uint4*)_ad = w; \
    w.x = pk2bf(ra[2].x, ra[2].y); w.y = pk2bf(ra[2].z, ra[2].w); \
    w.z = pk2bf(ra[3].x, ra[3].y); w.w = pk2bf(ra[3].z, ra[3].w); \
    *(uint4*)(_ad + 8) = w; \
    w.x = pk2bf(rb[0].x, rb[0].y); w.y = pk2bf(rb[0].z, rb[0].w); \
    w.z = pk2bf(rb[1].x, rb[1].y); w.w = pk2bf(rb[1].z, rb[1].w); \
    *(uint4*)_bd = w; \
    w.x = pk2bf(rb[2].x, rb[2].y); w.y = pk2bf(rb[2].z, rb[2].w); \
    w.z = pk2bf(rb[3].x, rb[3].y); w.w = pk2bf(rb[3].z, rb[3].w); \
    *(uint4*)(_bd + 8) = w; \
} while (0)

// Phase g: entry barrier already passed (slot (g+1)&1's readers done).
// ds_read frags of g -> cvt+write slice g+1 (compiler inserts the vmcnt for
// its regs; they were loaded one full phase ago) -> issue loads for g+2 ->
// MFMA g -> lgkmcnt(0) (writes visible) -> barrier.
#define PHASE(g, DW, DL) do { \
    const unsigned short* _a = &As[(g) & 1][0]; \
    const unsigned short* _b = &Bs[(g) & 1][0]; \
    short8 af[4], bf[4]; \
    _Pragma("unroll") for (int ii = 0; ii < 4; ++ii) { \
        af[ii] = *(const short8*)(_a + aoff + ii * 16 * LDT); \
        bf[ii] = *(const short8*)(_b + boff + ii * 16 * LDT); \
    } \
    if (DW) CVTWRITE((g) + 1); \
    if (DL) LOADREGS((g) + 2); \
    __builtin_amdgcn_s_setprio(1); \
    _Pragma("unroll") for (int ii = 0; ii < 4; ++ii) \
    _Pragma("unroll") for (int jj = 0; jj < 4; ++jj) \
        acc[ii][jj] = __builtin_amdgcn_mfma_f32_16x16x32_bf16(af[ii], bf[jj], acc[ii][jj], 0, 0, 0); \
    __builtin_amdgcn_s_setprio(0); \
    asm volatile("s_waitcnt lgkmcnt(0)" ::: "memory"); \
    BAR(); \
} while (0)

    // prologue: slice 0 into slot 0; issue slice-1 loads; sync
    LOADREGS(0);
    CVTWRITE(0);
    LOADREGS(1);
    asm volatile("s_waitcnt lgkmcnt(0)" ::: "memory");
    BAR();

    for (int g = 0; g < 14; ++g) PHASE(g, 1, 1);   // writes 1..14, loads 2..15
    PHASE(14, 1, 0);                               // writes slice 15
    PHASE(15, 0, 0);                               // tail

#undef PHASE
#undef CVTWRITE
#undef LOADREGS

    // epilogue (r6-verified): bias + softplus, packed {q,r} 4B stores
#pragma unroll
    for (int j = 0; j < 2; ++j) {
        const int h  = bn * 64 + (wn >> 1) + j * 16 + l15;  // 0..511
        const float bq = bias[h];
        const float br = bias[h + 512];
#pragma unroll
        for (int i = 0; i < 4; ++i) {
            const int mb = m0 + wm + i * 16 + l4 * 4;
#pragma unroll
            for (int r = 0; r < 4; ++r) {
                const float qv = softplus_f(acc[i][j][r] + bq);
                const float rv = softplus_f(acc[i][j + 2][r] + br);
                QR[(size_t)(mb + r) * 512 + h] = pk2bf(qv, rv);
            }
        }
    }
}

// ---------- Pass 2: chunked Kalman scan (r11-verified, unchanged) ----------
// 16 chunks of 256 steps, 64-step warm-up; 1 h-column/thread, 8-buffer
// rotation, depth-4 prefetch; ng in {32,40} -> unguarded COMP.
#define CHUNK 256
#define WARM 64

__global__ __launch_bounds__(256, 2)
void kalman_scan(const float* __restrict__ z,
                 const unsigned* __restrict__ QR,
                 float* __restrict__ out) {
    const int t     = threadIdx.x;
    const int hb    = blockIdx.x & 1;
    const int b     = (blockIdx.x >> 1) & 7;
    const int chunk = blockIdx.x >> 4;          // 0..15
    const int h     = hb * 256 + t;             // 0..511
    const int s0    = chunk << 8;               // chunk*256
    const int sw    = (chunk == 0) ? 0 : (s0 - WARM);
    const size_t base = ((size_t)(b * S_ + sw)) * 512 + h;

    const float*    zp  = z + base;             // stride 512 floats / step
    const unsigned* qrp = (const unsigned*)QR + base;
    float*          op  = out + base;

    const int ng    = ((s0 + CHUNK) - sw) >> 3;   // 32 (chunk 0) or 40
    const int skipg = (s0 - sw) >> 3;             // 0 or 8

    float    Z0[8], Z1[8], Z2[8], Z3[8], Z4[8], Z5[8], Z6[8], Z7[8];
    unsigned Q0[8], Q1[8], Q2[8], Q3[8], Q4[8], Q5[8], Q6[8], Q7[8];

#define LOADG(g, Zb, Qb) { const int _o = (g) * 8;                          \
    _Pragma("unroll") for (int u = 0; u < 8; ++u) {                         \
        Zb[u] = zp[(size_t)(_o + u) * 512]; Qb[u] = qrp[(size_t)(_o + u) * 512]; } }

#define COMP(g, Zb, Qb) { const int _o = (g) * 8; const bool _st = (g) >= skipg; \
    _Pragma("unroll") for (int u = 0; u < 8; ++u) {                         \
        const float q  = bf2f(Qb[u] & 0xffffu);                             \
        const float r  = bf2f(Qb[u] >> 16);                                 \
        const float Pp = P + q, rr = r + 1e-6f;                             \
        const float K  = Pp * __builtin_amdgcn_rcpf(Pp + rr);               \
        state = fmaf(K, Zb[u] - state, state); P = rr * K;                  \
        if (_st) op[(size_t)(_o + u) * 512] = state; } }

    LOADG(0, Z0, Q0); LOADG(1, Z1, Q1); LOADG(2, Z2, Q2); LOADG(3, Z3, Q3);

    float state = Z0[0];   // state init = z[sw]
    float P = 0.1f;

    for (int g = 0; g < ng; g += 8) {
        if (g + 4  < ng) LOADG(g + 4,  Z4, Q4); COMP(g,     Z0, Q0);
        if (g + 5  < ng) LOADG(g + 5,  Z5, Q5); COMP(g + 1, Z1, Q1);
        if (g + 6  < ng) LOADG(g + 6,  Z6, Q6); COMP(g + 2, Z2, Q2);
        if (g + 7  < ng) LOADG(g + 7,  Z7, Q7); COMP(g + 3, Z3, Q3);
        if (g + 8  < ng) LOADG(g + 8,  Z0, Q0); COMP(g + 4, Z4, Q4);
        if (g + 9  < ng) LOADG(g + 9,  Z1, Q1); COMP(g + 5, Z5, Q5);
        if (g + 10 < ng) LOADG(g + 10, Z2, Q2); COMP(g + 6, Z6, Q6);
        if (g + 11 < ng) LOADG(g + 11, Z3, Q3); COMP(g + 7, Z7, Q7);
    }
#undef LOADG
#undef COMP
}

extern "C" void kernel_launch(void* const* d_in, const int* in_sizes, int n_in,
                              void* d_out, int out_size, void* d_ws, size_t ws_size,
                              hipStream_t stream) {
    const float* lstm = (const float*)d_in[0];   // (8,4096,512) fp32
    const float* Wm   = (const float*)d_in[1];   // (1024,512)  fp32
    const float* bias = (const float*)d_in[2];   // (1024,)     fp32

    unsigned* QRw = (unsigned*)d_ws;             // packed {q,r} bf16x2, 64 MB

    // Fused GEMM reads fp32 inputs directly (convert pass deleted).
    // 256 M-tiles x 8 N-tiles = 2048 blocks of 256 threads (2 blocks/CU)
    hipLaunchKernelGGL(gemm_softplus, dim3(2048), dim3(256), 0, stream,
                       lstm, Wm, bias, QRw);

    // 2 h-halves * 8 batches * 16 chunks = 256 blocks of 256 threads
    hipLaunchKernelGGL(kalman_scan, dim3(256), dim3(256), 0, stream,
                       lstm, QRw, (float*)d_out);
}